// Round 6
// baseline (551.099 us; speedup 1.0000x reference)
//
#include <hip/hip_runtime.h>
#include <hip/hip_bf16.h>
#include <stdint.h>

#define S_LEN 2048
#define NB 2
#define NH 16
#define HDIM 128
#define RDIM 64
#define DF 192          // HDIM + RDIM
#define MROWS 4096      // NB * S_LEN

typedef __bf16 bf16_t;
typedef __attribute__((ext_vector_type(8))) __bf16 bf16x8;
typedef __attribute__((ext_vector_type(4))) __bf16 bf16x4;
typedef __attribute__((ext_vector_type(4))) float f32x4;
typedef __attribute__((ext_vector_type(4))) float float4v;

__device__ __forceinline__ void gload_lds16(const bf16_t* g, bf16_t* l) {
  __builtin_amdgcn_global_load_lds(
      (const __attribute__((address_space(1))) void*)g,
      (__attribute__((address_space(3))) void*)l, 16, 0, 0);
}

// ---------------- convert f32 -> bf16 (contiguous) ----------------
__global__ __launch_bounds__(256) void convert_bf16(const float* __restrict__ in,
                                                    bf16_t* __restrict__ out, int n4) {
  int i = blockIdx.x * 256 + threadIdx.x;
  if (i >= n4) return;
  float4v v = *reinterpret_cast<const float4v*>(&in[(size_t)i * 4]);
  bf16x4 o;
  o[0] = (bf16_t)v[0]; o[1] = (bf16_t)v[1]; o[2] = (bf16_t)v[2]; o[3] = (bf16_t)v[3];
  *reinterpret_cast<bf16x4*>(&out[(size_t)i * 4]) = o;
}

// ---------------- transpose (K,N) f32 -> (N,K) bf16 ----------------
__global__ __launch_bounds__(256) void transpose_bf16(const float* __restrict__ in,
                                                      bf16_t* __restrict__ out,
                                                      int K, int N) {
  __shared__ float t[64][65];
  const int n0 = blockIdx.x * 64, k0 = blockIdx.y * 64;
  const int tx = threadIdx.x & 63, ty = threadIdx.x >> 6;
#pragma unroll
  for (int i = ty; i < 64; i += 4)
    t[i][tx] = in[(size_t)(k0 + i) * N + n0 + tx];
  __syncthreads();
#pragma unroll
  for (int i = ty; i < 64; i += 4)
    out[(size_t)(n0 + i) * K + k0 + tx] = (bf16_t)t[tx][i];
}

// ---------------- GEMM: C(M,N) = A(M,K) * Bt(N,K)^T ----------------
// MODE 1: f32 out + bias (final projection)
// MODE 5: fused xb@[Wlq|Wkv|Wkr]: col<1536 -> cq ; col<2048 -> ckv ; else kr rope->kf
// MODE 6: fused cq@[Wq|Wqr]:      col<2048 -> qf d<128 ; else qr rope->qf
// MODE 7: fused ckv@[Wk|Wv]:      col<2048 -> kf d<128 ; else v -> vT
struct EpiParams {
  bf16_t* o0;
  bf16_t* o1;
  bf16_t* o2;
  float* outf;
  const float* bias;
  const float* cosb;
  const float* sinb;
};

template <int MODE>
__global__ __launch_bounds__(256) void gemm_bt(const bf16_t* __restrict__ A,
                                               const bf16_t* __restrict__ Bt,
                                               int M, int N, int K, EpiParams ep) {
  const int tid = threadIdx.x;
  const int lane = tid & 63, w = tid >> 6;
  const int l15 = lane & 15, lg = lane >> 4;
  // T1: XCD-aware block swizzle (all grids have nwg % 8 == 0).
  const int gx = gridDim.x;
  const int nwg = gx * gridDim.y;
  int flat = blockIdx.y * gx + blockIdx.x;
  flat = (flat & 7) * (nwg >> 3) + (flat >> 3);
  const int m0 = (flat / gx) * 128, n0 = (flat % gx) * 128;
  const int mw = (w >> 1) * 64, nw = (w & 1) * 64;
  __shared__ alignas(16) bf16_t As[128 * 32];
  __shared__ alignas(16) bf16_t Bs[128 * 32];

  f32x4 acc[4][4] = {};
  const int row_ld = tid >> 2;            // 0..63
  const int col8 = (tid & 3) * 8;
  const bf16_t* ag = A + (size_t)(m0 + row_ld) * K + col8;
  const bf16_t* bg = Bt + (size_t)(n0 + row_ld) * K + col8;
  const unsigned wbase = (unsigned)(tid & ~63u) * 8;  // elems

  for (int k0 = 0; k0 < K; k0 += 32) {
    __syncthreads();
    gload_lds16(ag + k0, As + wbase);
    gload_lds16(ag + (size_t)64 * K + k0, As + 2048 + wbase);
    gload_lds16(bg + k0, Bs + wbase);
    gload_lds16(bg + (size_t)64 * K + k0, Bs + 2048 + wbase);
    __syncthreads();
    bf16x8 a[4], b[4];
#pragma unroll
    for (int i = 0; i < 4; ++i)
      a[i] = *reinterpret_cast<const bf16x8*>(&As[(mw + i * 16 + l15) * 32 + lg * 8]);
#pragma unroll
    for (int i = 0; i < 4; ++i)
      b[i] = *reinterpret_cast<const bf16x8*>(&Bs[(nw + i * 16 + l15) * 32 + lg * 8]);
#pragma unroll
    for (int i = 0; i < 4; ++i)
#pragma unroll
      for (int j = 0; j < 4; ++j)
        acc[i][j] = __builtin_amdgcn_mfma_f32_16x16x32_bf16(a[i], b[j], acc[i][j], 0, 0, 0);
  }

#pragma unroll
  for (int i = 0; i < 4; ++i)
#pragma unroll
    for (int j = 0; j < 4; ++j) {
      const int col = n0 + nw + j * 16 + l15;
#pragma unroll
      for (int r = 0; r < 4; ++r) {
        const int row = m0 + mw + i * 16 + lg * 4 + r;
        float v = acc[i][j][r];
        const int b = row >> 11, s = row & 2047;
        if constexpr (MODE == 1) {
          ep.outf[(size_t)row * N + col] = v + ep.bias[col];
        } else if constexpr (MODE == 5) {
          if (col < 1536) {
            ep.o0[(size_t)row * 1536 + col] = (bf16_t)v;
          } else if (col < 2048) {
            ep.o1[(size_t)row * 512 + (col - 1536)] = (bf16_t)v;
          } else {
            const int c2 = col - 2048;
            float vb = v + ep.bias[c2];
            float other = __shfl_xor(vb, 1, 64);
            const int h = c2 >> 6, dr = c2 & 63;
            const int fi = dr >> 1;
            const float c = ep.cosb[s * 32 + fi];
            const float sn = ep.sinb[s * 32 + fi];
            const float o = (c2 & 1) ? (other * sn + vb * c) : (vb * c - other * sn);
            ep.o2[(((size_t)(b * NH + h)) * S_LEN + s) * DF + 128 + dr] = (bf16_t)o;
          }
        } else if constexpr (MODE == 6) {
          if (col < 2048) {
            const int h = col >> 7, d = col & 127;
            ep.o0[(((size_t)(b * NH + h)) * S_LEN + s) * DF + d] = (bf16_t)v;
          } else {
            const int c2 = col - 2048;
            float vb = v + ep.bias[c2];
            float other = __shfl_xor(vb, 1, 64);
            const int h = c2 >> 6, dr = c2 & 63;
            const int fi = dr >> 1;
            const float c = ep.cosb[s * 32 + fi];
            const float sn = ep.sinb[s * 32 + fi];
            const float o = (c2 & 1) ? (other * sn + vb * c) : (vb * c - other * sn);
            ep.o0[(((size_t)(b * NH + h)) * S_LEN + s) * DF + 128 + dr] = (bf16_t)o;
          }
        } else {  // MODE 7
          if (col < 2048) {
            const int h = col >> 7, d = col & 127;
            ep.o0[(((size_t)(b * NH + h)) * S_LEN + s) * DF + d] = (bf16_t)v;
          } else {
            const int c2 = col - 2048;
            const int h = c2 >> 7, d = c2 & 127;
            ep.o1[(((size_t)(b * NH + h)) * HDIM + d) * S_LEN + s] = (bf16_t)v;
          }
        }
      }
    }
}

// ---------------- flash attention (causal), T14 reg-staged pipeline ----------------
// qf,kf: (B,H,S,192) bf16 ; vT: (B,H,128,S) bf16 ; att: (B,S,H*128) bf16
// Block: 8 waves x 16 q-rows = 128 q rows. KV tile = 64 keys.
// K: SINGLE 24KB LDS buffer, reg-staged (T14): loads issued at iter top fly under
//    the whole tile compute; ds_write after the post-compute barrier.
// V: global_load_lds double-buffer (32KB), counted vmcnt (issued 1 iter ahead).
// Ps: per-wave 16KB. Total 72KB -> 2 blocks/CU = 16 waves/CU.
// 2 raw s_barriers per iteration; vmcnt never drained to 0 in the loop.
__global__ __launch_bounds__(512, 4) void attn_fwd(const bf16_t* __restrict__ qf,
                                                   const bf16_t* __restrict__ kf,
                                                   const bf16_t* __restrict__ vT,
                                                   bf16_t* __restrict__ att) {
  const int tid = threadIdx.x;
  const int lane = tid & 63, w = tid >> 6;   // w: 0..7
  const int l15 = lane & 15, lg = lane >> 4;
  // XCD-grouped swizzle: block l -> XCD l%8; 4 bh per XCD, heavy q first.
  const int l = blockIdx.x;                  // 0..511
  const int bh = (l & 7) * 4 + ((l >> 3) & 3);
  const int qchunk = l >> 5;                 // 0..15
  const int qb0 = (15 - qchunk) * 128;
  const int q0 = qb0 + w * 16;
  const float scale = 0.07216878364870322f;  // 1/sqrt(192)

  __shared__ alignas(16) bf16_t Ks[64 * 192];      // 24 KB single (swizzled content)
  __shared__ alignas(16) bf16_t Vs[2][128 * 64];   // 32 KB dbuf (swizzled content)
  __shared__ alignas(16) bf16_t Ps[8 * 16 * 64];   // 16 KB per-wave P

  // Q fragments held for the whole loop
  const bf16_t* qptr = qf + ((size_t)bh * S_LEN + q0 + l15) * DF + lg * 8;
  bf16x8 qfr[6];
#pragma unroll
  for (int d = 0; d < 6; ++d) qfr[d] = *reinterpret_cast<const bf16x8*>(qptr + d * 32);

  f32x4 o[8] = {};
  float m[4], lsum[4];
#pragma unroll
  for (int r = 0; r < 4; ++r) { m[r] = -1e30f; lsum[r] = 0.0f; }

  const bf16_t* kb0 = kf + (size_t)bh * S_LEN * DF;
  const bf16_t* vb0 = vT + (size_t)bh * HDIM * S_LEN;
  const int njt = qb0 / 64 + 2;
  const int wslot = tid & ~63;

  // K reg-stage: 3 x 16B per thread. slot s=i*512+tid; row=s/24, c=s%24 (natural).
  bf16x8 kst0, kst1, kst2;
  auto issueK = [&](int jtile) {
    const bf16_t* kTile = kb0 + (size_t)jtile * 64 * DF;
    {
      const int s = tid;          const int row = s / 24, c = s - row * 24;
      kst0 = *reinterpret_cast<const bf16x8*>(kTile + (size_t)row * DF + c * 8);
    }
    {
      const int s = 512 + tid;    const int row = s / 24, c = s - row * 24;
      kst1 = *reinterpret_cast<const bf16x8*>(kTile + (size_t)row * DF + c * 8);
    }
    {
      const int s = 1024 + tid;   const int row = s / 24, c = s - row * 24;
      kst2 = *reinterpret_cast<const bf16x8*>(kTile + (size_t)row * DF + c * 8);
    }
  };
  auto writeK = [&]() {
    {
      const int s = tid;          const int row = s / 24, c = s - row * 24;
      *reinterpret_cast<bf16x8*>(&Ks[row * 192 + (c ^ (row & 7)) * 8]) = kst0;
    }
    {
      const int s = 512 + tid;    const int row = s / 24, c = s - row * 24;
      *reinterpret_cast<bf16x8*>(&Ks[row * 192 + (c ^ (row & 7)) * 8]) = kst1;
    }
    {
      const int s = 1024 + tid;   const int row = s / 24, c = s - row * 24;
      *reinterpret_cast<bf16x8*>(&Ks[row * 192 + (c ^ (row & 7)) * 8]) = kst2;
    }
  };
  auto stageV = [&](int jtile, int buf) {
    const bf16_t* vTile = vb0 + jtile * 64;
#pragma unroll
    for (int i = 0; i < 2; ++i) {
      const int s = i * 512 + tid;
      const int row = s >> 3, c = s & 7;
      const int cs = c ^ (row & 7);
      gload_lds16(vTile + (size_t)row * S_LEN + cs * 8,
                  &Vs[buf][(size_t)(i * 512 + wslot) * 8]);
    }
  };

  // ---- prologue: tile 0 fully staged ----
  issueK(0);
  stageV(0, 0);
  asm volatile("s_waitcnt vmcnt(0)" ::: "memory");
  writeK();
  asm volatile("s_waitcnt lgkmcnt(0)" ::: "memory");
  __builtin_amdgcn_s_barrier();

  for (int jt = 0; jt < njt; ++jt) {
    const int j0 = jt * 64;
    const int cur = jt & 1;
    const int jn = (jt + 1 < njt) ? jt + 1 : jt;
    // issue next tile: K -> regs (3 loads), V -> Vs[cur^1] (2 gload_lds)
    issueK(jn);
    stageV(jn, cur ^ 1);

    const bool active = (j0 <= q0 + 15);
    if (active) {
      // ---- QK^T from Ks ----
      f32x4 sa[4] = {};
      __builtin_amdgcn_s_setprio(1);
#pragma unroll
      for (int jf = 0; jf < 4; ++jf) {
        const int krow = jf * 16 + l15;
        const int ksw = krow & 7;
#pragma unroll
        for (int d = 0; d < 6; ++d) {
          const int kc = (4 * d + lg) ^ ksw;
          bf16x8 kfr = *reinterpret_cast<const bf16x8*>(&Ks[krow * 192 + kc * 8]);
          sa[jf] = __builtin_amdgcn_mfma_f32_16x16x32_bf16(qfr[d], kfr, sa[jf], 0, 0, 0);
        }
      }
      __builtin_amdgcn_s_setprio(0);

      const bool full = (j0 + 63 <= q0);
      float sv[16];
#pragma unroll
      for (int jf = 0; jf < 4; ++jf)
#pragma unroll
        for (int r = 0; r < 4; ++r) {
          float x = sa[jf][r] * scale;
          if (!full) {
            const int j = j0 + jf * 16 + l15;
            const int qi = q0 + lg * 4 + r;
            if (j > qi) x = -1e30f;
          }
          sv[jf * 4 + r] = x;
        }

      float tmax[4];
#pragma unroll
      for (int r = 0; r < 4; ++r)
        tmax[r] = fmaxf(fmaxf(sv[r], sv[4 + r]), fmaxf(sv[8 + r], sv[12 + r]));
#pragma unroll
      for (int xm = 1; xm < 16; xm <<= 1)
#pragma unroll
        for (int r = 0; r < 4; ++r) tmax[r] = fmaxf(tmax[r], __shfl_xor(tmax[r], xm, 64));
      float alpha[4];
#pragma unroll
      for (int r = 0; r < 4; ++r) {
        const float mn = fmaxf(m[r], tmax[r]);
        alpha[r] = __expf(m[r] - mn);
        m[r] = mn;
      }
#pragma unroll
      for (int jf = 0; jf < 4; ++jf)
#pragma unroll
        for (int r = 0; r < 4; ++r) sv[jf * 4 + r] = __expf(sv[jf * 4 + r] - m[r]);
      float rs[4];
#pragma unroll
      for (int r = 0; r < 4; ++r)
        rs[r] = (sv[r] + sv[4 + r]) + (sv[8 + r] + sv[12 + r]);
#pragma unroll
      for (int xm = 1; xm < 16; xm <<= 1)
#pragma unroll
        for (int r = 0; r < 4; ++r) rs[r] += __shfl_xor(rs[r], xm, 64);
#pragma unroll
      for (int r = 0; r < 4; ++r) lsum[r] = lsum[r] * alpha[r] + rs[r];
#pragma unroll
      for (int t = 0; t < 8; ++t)
#pragma unroll
        for (int r = 0; r < 4; ++r) o[t][r] *= alpha[r];

      // ---- P roundtrip (per-wave swizzled LDS) ----
#pragma unroll
      for (int jf = 0; jf < 4; ++jf)
#pragma unroll
        for (int r = 0; r < 4; ++r) {
          const int row = lg * 4 + r, col = jf * 16 + l15;
          Ps[w * 1024 + row * 64 + (((col >> 3) ^ (row & 7)) << 3) + (col & 7)] =
              (bf16_t)sv[jf * 4 + r];
        }
      asm volatile("s_waitcnt lgkmcnt(0)" ::: "memory");
      __builtin_amdgcn_sched_barrier(0);
      bf16x8 pfr[2];
#pragma unroll
      for (int jk = 0; jk < 2; ++jk)
        pfr[jk] = *reinterpret_cast<const bf16x8*>(
            &Ps[w * 1024 + l15 * 64 + (((jk * 4 + lg) ^ (l15 & 7)) << 3)]);

      // V[jt] (issued last iter) landed; leave this iter's K(3)+V(2) in flight
      asm volatile("s_waitcnt vmcnt(5)" ::: "memory");
      __builtin_amdgcn_s_setprio(1);
#pragma unroll
      for (int dt = 0; dt < 8; ++dt) {
        const int vrow = dt * 16 + l15;
        const int vsw = vrow & 7;
#pragma unroll
        for (int jk = 0; jk < 2; ++jk) {
          const int vc = (jk * 4 + lg) ^ vsw;
          bf16x8 vfr = *reinterpret_cast<const bf16x8*>(&Vs[cur][vrow * 64 + vc * 8]);
          o[dt] = __builtin_amdgcn_mfma_f32_16x16x32_bf16(pfr[jk], vfr, o[dt], 0, 0, 0);
        }
      }
      __builtin_amdgcn_s_setprio(0);
    }

    // K[jn] regs landed (leave V[jn]'s 2 gload_lds in flight)
    asm volatile("s_waitcnt vmcnt(2)" ::: "memory");
    __builtin_amdgcn_s_barrier();   // all waves done reading Ks (K[jt])
    writeK();                        // K[jn] -> Ks (swizzled)
    asm volatile("s_waitcnt lgkmcnt(0)" ::: "memory");
    __builtin_amdgcn_s_barrier();   // K[jn] visible to all
  }

  float inv[4];
#pragma unroll
  for (int r = 0; r < 4; ++r) inv[r] = 1.0f / lsum[r];
  const int b = bh >> 4, h = bh & 15;
#pragma unroll
  for (int dt = 0; dt < 8; ++dt)
#pragma unroll
    for (int r = 0; r < 4; ++r) {
      const int s = q0 + lg * 4 + r;
      att[((size_t)b * S_LEN + s) * 2048 + h * 128 + dt * 16 + l15] =
          (bf16_t)(o[dt][r] * inv[r]);
    }
}

// ---------------- host launch ----------------
extern "C" void kernel_launch(void* const* d_in, const int* in_sizes, int n_in,
                              void* d_out, int out_size, void* d_ws, size_t ws_size,
                              hipStream_t stream) {
  const float* x    = (const float*)d_in[0];
  const float* fcos = (const float*)d_in[1];
  const float* fsin = (const float*)d_in[2];
  const float* Wkv  = (const float*)d_in[3];
  const float* Wlq  = (const float*)d_in[4];
  const float* Wq   = (const float*)d_in[5];
  const float* Wk   = (const float*)d_in[6];
  const float* Wv   = (const float*)d_in[7];
  const float* Wqr  = (const float*)d_in[8];
  const float* bqr  = (const float*)d_in[9];
  const float* Wkr  = (const float*)d_in[10];
  const float* bkr  = (const float*)d_in[11];
  const float* Wo   = (const float*)d_in[12];
  const float* bo   = (const float*)d_in[13];
  float* out = (float*)d_out;

  char* ws = (char*)d_ws;
  size_t off = 0;
  auto alloc = [&](size_t bytes) {
    void* p = ws + off;
    off += (bytes + 255) & ~(size_t)255;
    return p;
  };
  bf16_t* xb    = (bf16_t*)alloc((size_t)MROWS * 2048 * 2);
  bf16_t* WcatA = (bf16_t*)alloc((size_t)3072 * 2048 * 2);  // [Wlq|Wkv|Wkr]^T, K=2048
  bf16_t* WcatB = (bf16_t*)alloc((size_t)3072 * 1536 * 2);  // [Wq|Wqr]^T,     K=1536
  bf16_t* WcatC = (bf16_t*)alloc((size_t)4096 * 512 * 2);   // [Wk|Wv]^T,      K=512
  bf16_t* WoT   = (bf16_t*)alloc((size_t)2048 * 2048 * 2);
  bf16_t* cq    = (bf16_t*)alloc((size_t)MROWS * 1536 * 2);
  bf16_t* ckv   = (bf16_t*)alloc((size_t)MROWS * 512 * 2);
  bf16_t* qfb   = (bf16_t*)alloc((size_t)NB * NH * S_LEN * DF * 2);
  bf16_t* kfb   = (bf16_t*)alloc((size_t)NB * NH * S_LEN * DF * 2);
  bf16_t* vTb   = (bf16_t*)alloc((size_t)NB * NH * HDIM * S_LEN * 2);
  bf16_t* attb  = (bf16_t*)alloc((size_t)MROWS * 2048 * 2);

  // 1. convert x
  {
    int n4 = (MROWS * 2048) / 4;
    convert_bf16<<<dim3((n4 + 255) / 256), dim3(256), 0, stream>>>(x, xb, n4);
  }
  // 2. transpose weights into concatenated (N,K) bf16 buffers
  auto tr = [&](const float* in, bf16_t* o_, int K, int N) {
    transpose_bf16<<<dim3(N / 64, K / 64), dim3(256), 0, stream>>>(in, o_, K, N);
  };
  tr(Wlq, WcatA, 2048, 1536);
  tr(Wkv, WcatA + (size_t)1536 * 2048, 2048, 512);
  tr(Wkr, WcatA + (size_t)2048 * 2048, 2048, 1024);
  tr(Wq,  WcatB, 1536, 2048);
  tr(Wqr, WcatB + (size_t)2048 * 1536, 1536, 1024);
  tr(Wk,  WcatC, 512, 2048);
  tr(Wv,  WcatC + (size_t)2048 * 512, 512, 2048);
  tr(Wo,  WoT, 2048, 2048);

  EpiParams ep{};

  // 3. fused: [cq | ckv | kr-rope->kf] = xb @ WcatA^T   (N=3072, K=2048)
  ep = {cq, ckv, kfb, nullptr, bkr, fcos, fsin};
  gemm_bt<5><<<dim3(3072 / 128, MROWS / 128), dim3(256), 0, stream>>>(
      xb, WcatA, MROWS, 3072, 2048, ep);
  // 4. fused: [q->qf | qr-rope->qf] = cq @ WcatB^T      (N=3072, K=1536)
  ep = {qfb, nullptr, nullptr, nullptr, bqr, fcos, fsin};
  gemm_bt<6><<<dim3(3072 / 128, MROWS / 128), dim3(256), 0, stream>>>(
      cq, WcatB, MROWS, 3072, 1536, ep);
  // 5. fused: [k->kf | v->vT] = ckv @ WcatC^T           (N=4096, K=512)
  ep = {kfb, vTb, nullptr, nullptr, nullptr, nullptr, nullptr};
  gemm_bt<7><<<dim3(4096 / 128, MROWS / 128), dim3(256), 0, stream>>>(
      ckv, WcatC, MROWS, 4096, 512, ep);
  // 6. attention: 1D grid, XCD-grouped swizzle inside the kernel
  attn_fwd<<<dim3(512), dim3(512), 0, stream>>>(qfb, kfb, vTb, attb);
  // 7. out = att @ Wo + bo  (f32)
  ep = {nullptr, nullptr, nullptr, out, bo, nullptr, nullptr};
  gemm_bt<1><<<dim3(2048 / 128, MROWS / 128), dim3(256), 0, stream>>>(
      attb, WoT, MROWS, 2048, 2048, ep);
}

// Round 7
// 389.179 us; speedup vs baseline: 1.4161x; 1.4161x over previous
//
#include <hip/hip_runtime.h>
#include <hip/hip_bf16.h>
#include <stdint.h>

#define S_LEN 2048
#define NB 2
#define NH 16
#define HDIM 128
#define RDIM 64
#define DF 192          // HDIM + RDIM
#define MROWS 4096      // NB * S_LEN

typedef __bf16 bf16_t;
typedef __attribute__((ext_vector_type(8))) __bf16 bf16x8;
typedef __attribute__((ext_vector_type(4))) __bf16 bf16x4;
typedef __attribute__((ext_vector_type(4))) float f32x4;
typedef __attribute__((ext_vector_type(4))) float float4v;

__device__ __forceinline__ void gload_lds16(const bf16_t* g, bf16_t* l) {
  __builtin_amdgcn_global_load_lds(
      (const __attribute__((address_space(1))) void*)g,
      (__attribute__((address_space(3))) void*)l, 16, 0, 0);
}

// ---------------- convert f32 -> bf16 (contiguous) ----------------
__global__ __launch_bounds__(256) void convert_bf16(const float* __restrict__ in,
                                                    bf16_t* __restrict__ out, int n4) {
  int i = blockIdx.x * 256 + threadIdx.x;
  if (i >= n4) return;
  float4v v = *reinterpret_cast<const float4v*>(&in[(size_t)i * 4]);
  bf16x4 o;
  o[0] = (bf16_t)v[0]; o[1] = (bf16_t)v[1]; o[2] = (bf16_t)v[2]; o[3] = (bf16_t)v[3];
  *reinterpret_cast<bf16x4*>(&out[(size_t)i * 4]) = o;
}

// ---------------- transpose (K,N) f32 -> (N,K) bf16 ----------------
__global__ __launch_bounds__(256) void transpose_bf16(const float* __restrict__ in,
                                                      bf16_t* __restrict__ out,
                                                      int K, int N) {
  __shared__ float t[64][65];
  const int n0 = blockIdx.x * 64, k0 = blockIdx.y * 64;
  const int tx = threadIdx.x & 63, ty = threadIdx.x >> 6;
#pragma unroll
  for (int i = ty; i < 64; i += 4)
    t[i][tx] = in[(size_t)(k0 + i) * N + n0 + tx];
  __syncthreads();
#pragma unroll
  for (int i = ty; i < 64; i += 4)
    out[(size_t)(n0 + i) * K + k0 + tx] = (bf16_t)t[tx][i];
}

// ---------------- GEMM: C(M,N) = A(M,K) * Bt(N,K)^T ----------------
// MODE 1: f32 out + bias (final projection)
// MODE 5: fused xb@[Wlq|Wkv|Wkr]: col<1536 -> cq ; col<2048 -> ckv ; else kr rope->kf
// MODE 6: fused cq@[Wq|Wqr]:      col<2048 -> qf d<128 ; else qr rope->qf
// MODE 7: fused ckv@[Wk|Wv]:      col<2048 -> kf d<128 ; else v -> vT
struct EpiParams {
  bf16_t* o0;
  bf16_t* o1;
  bf16_t* o2;
  float* outf;
  const float* bias;
  const float* cosb;
  const float* sinb;
};

template <int MODE>
__global__ __launch_bounds__(256) void gemm_bt(const bf16_t* __restrict__ A,
                                               const bf16_t* __restrict__ Bt,
                                               int M, int N, int K, EpiParams ep) {
  const int tid = threadIdx.x;
  const int lane = tid & 63, w = tid >> 6;
  const int l15 = lane & 15, lg = lane >> 4;
  // T1: XCD-aware block swizzle (all grids have nwg % 8 == 0).
  const int gx = gridDim.x;
  const int nwg = gx * gridDim.y;
  int flat = blockIdx.y * gx + blockIdx.x;
  flat = (flat & 7) * (nwg >> 3) + (flat >> 3);
  const int m0 = (flat / gx) * 128, n0 = (flat % gx) * 128;
  const int mw = (w >> 1) * 64, nw = (w & 1) * 64;
  __shared__ alignas(16) bf16_t As[128 * 32];
  __shared__ alignas(16) bf16_t Bs[128 * 32];

  f32x4 acc[4][4] = {};
  const int row_ld = tid >> 2;            // 0..63
  const int col8 = (tid & 3) * 8;
  const bf16_t* ag = A + (size_t)(m0 + row_ld) * K + col8;
  const bf16_t* bg = Bt + (size_t)(n0 + row_ld) * K + col8;
  const unsigned wbase = (unsigned)(tid & ~63u) * 8;  // elems

  for (int k0 = 0; k0 < K; k0 += 32) {
    __syncthreads();
    gload_lds16(ag + k0, As + wbase);
    gload_lds16(ag + (size_t)64 * K + k0, As + 2048 + wbase);
    gload_lds16(bg + k0, Bs + wbase);
    gload_lds16(bg + (size_t)64 * K + k0, Bs + 2048 + wbase);
    __syncthreads();
    bf16x8 a[4], b[4];
#pragma unroll
    for (int i = 0; i < 4; ++i)
      a[i] = *reinterpret_cast<const bf16x8*>(&As[(mw + i * 16 + l15) * 32 + lg * 8]);
#pragma unroll
    for (int i = 0; i < 4; ++i)
      b[i] = *reinterpret_cast<const bf16x8*>(&Bs[(nw + i * 16 + l15) * 32 + lg * 8]);
#pragma unroll
    for (int i = 0; i < 4; ++i)
#pragma unroll
      for (int j = 0; j < 4; ++j)
        acc[i][j] = __builtin_amdgcn_mfma_f32_16x16x32_bf16(a[i], b[j], acc[i][j], 0, 0, 0);
  }

#pragma unroll
  for (int i = 0; i < 4; ++i)
#pragma unroll
    for (int j = 0; j < 4; ++j) {
      const int col = n0 + nw + j * 16 + l15;
#pragma unroll
      for (int r = 0; r < 4; ++r) {
        const int row = m0 + mw + i * 16 + lg * 4 + r;
        float v = acc[i][j][r];
        const int b = row >> 11, s = row & 2047;
        if constexpr (MODE == 1) {
          ep.outf[(size_t)row * N + col] = v + ep.bias[col];
        } else if constexpr (MODE == 5) {
          if (col < 1536) {
            ep.o0[(size_t)row * 1536 + col] = (bf16_t)v;
          } else if (col < 2048) {
            ep.o1[(size_t)row * 512 + (col - 1536)] = (bf16_t)v;
          } else {
            const int c2 = col - 2048;
            float vb = v + ep.bias[c2];
            float other = __shfl_xor(vb, 1, 64);
            const int h = c2 >> 6, dr = c2 & 63;
            const int fi = dr >> 1;
            const float c = ep.cosb[s * 32 + fi];
            const float sn = ep.sinb[s * 32 + fi];
            const float o = (c2 & 1) ? (other * sn + vb * c) : (vb * c - other * sn);
            ep.o2[(((size_t)(b * NH + h)) * S_LEN + s) * DF + 128 + dr] = (bf16_t)o;
          }
        } else if constexpr (MODE == 6) {
          if (col < 2048) {
            const int h = col >> 7, d = col & 127;
            ep.o0[(((size_t)(b * NH + h)) * S_LEN + s) * DF + d] = (bf16_t)v;
          } else {
            const int c2 = col - 2048;
            float vb = v + ep.bias[c2];
            float other = __shfl_xor(vb, 1, 64);
            const int h = c2 >> 6, dr = c2 & 63;
            const int fi = dr >> 1;
            const float c = ep.cosb[s * 32 + fi];
            const float sn = ep.sinb[s * 32 + fi];
            const float o = (c2 & 1) ? (other * sn + vb * c) : (vb * c - other * sn);
            ep.o0[(((size_t)(b * NH + h)) * S_LEN + s) * DF + 128 + dr] = (bf16_t)o;
          }
        } else {  // MODE 7
          if (col < 2048) {
            const int h = col >> 7, d = col & 127;
            ep.o0[(((size_t)(b * NH + h)) * S_LEN + s) * DF + d] = (bf16_t)v;
          } else {
            const int c2 = col - 2048;
            const int h = c2 >> 7, d = c2 & 127;
            ep.o1[(((size_t)(b * NH + h)) * HDIM + d) * S_LEN + s] = (bf16_t)v;
          }
        }
      }
    }
}

// ---------------- flash attention (causal), swapped-QK^T softmax ----------------
// qf,kf: (B,H,S,192) bf16 ; vT: (B,H,128,S) bf16 ; att: (B,S,H*128) bf16
// Block: 8 waves x 16 q-rows = 128 q rows. KV tile = 64 keys, staged to LDS
// (r3-proven 2-barrier global_load_lds form). SWAPPED QK^T: sa = mfma(K, Q)
// puts one query per lane column -> softmax is an in-register tree + 2
// shfl_xor rounds (vs 8 before). Defer-max (T13, THR=8) skips O-rescale on
// most tiles. P roundtrips through swizzled per-wave LDS as before.
// LDS 56 KB -> 2 blocks/CU.
__global__ __launch_bounds__(512, 4) void attn_fwd(const bf16_t* __restrict__ qf,
                                                   const bf16_t* __restrict__ kf,
                                                   const bf16_t* __restrict__ vT,
                                                   bf16_t* __restrict__ att) {
  const int tid = threadIdx.x;
  const int lane = tid & 63, w = tid >> 6;   // w: 0..7
  const int l15 = lane & 15, lg = lane >> 4;
  // XCD-grouped swizzle: block l -> XCD l%8; 4 bh per XCD, heavy q first.
  const int l = blockIdx.x;                  // 0..511
  const int bh = (l & 7) * 4 + ((l >> 3) & 3);
  const int qchunk = l >> 5;                 // 0..15
  const int qb0 = (15 - qchunk) * 128;
  const int q0 = qb0 + w * 16;
  const float scale = 0.07216878364870322f;  // 1/sqrt(192)

  __shared__ alignas(16) bf16_t Ks[64 * 192];     // 24 KB (swizzled)
  __shared__ alignas(16) bf16_t Vs[128 * 64];     // 16 KB (swizzled)
  __shared__ alignas(16) bf16_t Ps[8 * 16 * 64];  // 16 KB per-wave P (swizzled)

  // Q fragments (B-operand) held for the whole loop
  const bf16_t* qptr = qf + ((size_t)bh * S_LEN + q0 + l15) * DF + lg * 8;
  bf16x8 qfr[6];
#pragma unroll
  for (int d = 0; d < 6; ++d) qfr[d] = *reinterpret_cast<const bf16x8*>(qptr + d * 32);

  f32x4 o[8] = {};
  float mrun = -1e30f, lsum = 0.0f;  // per-lane state for query q0 + l15

  const bf16_t* kb0 = kf + (size_t)bh * S_LEN * DF;
  const bf16_t* vb0 = vT + (size_t)bh * HDIM * S_LEN;
  const int njt = qb0 / 64 + 2;
  const int wslot = tid & ~63;

  for (int jt = 0; jt < njt; ++jt) {
    const int j0 = jt * 64;
    __syncthreads();  // previous tile's reads complete before overwrite
    // ---- stage K tile: 64 rows x 384B = 1536 16B-slots, 3 issues x 512 ----
    const bf16_t* kTile = kb0 + (size_t)j0 * DF;
#pragma unroll
    for (int i = 0; i < 3; ++i) {
      const int s = i * 512 + tid;
      const int row = s / 24;
      const int c = s - row * 24;
      const int cs = c ^ (row & 7);
      gload_lds16(kTile + (size_t)row * DF + cs * 8,
                  Ks + (size_t)(i * 512 + wslot) * 8);
    }
    // ---- stage V tile: 128 rows x 128B = 1024 16B-slots, 2 issues x 512 ----
    const bf16_t* vTile = vb0 + j0;
#pragma unroll
    for (int i = 0; i < 2; ++i) {
      const int s = i * 512 + tid;
      const int row = s >> 3;
      const int c = s & 7;
      const int cs = c ^ (row & 7);
      gload_lds16(vTile + (size_t)row * S_LEN + cs * 8,
                  Vs + (size_t)(i * 512 + wslot) * 8);
    }
    __syncthreads();  // staged data visible

    if (j0 > q0 + 15) continue;  // fully masked for this wave

    // ---- QK^T SWAPPED: sa[jf] = K_frag x Q_frag -> row=key, col=query ----
    f32x4 sa[4] = {};
    __builtin_amdgcn_s_setprio(1);
#pragma unroll
    for (int jf = 0; jf < 4; ++jf) {
      const int krow = jf * 16 + l15;
      const int ksw = krow & 7;
#pragma unroll
      for (int d = 0; d < 6; ++d) {
        const int kc = (4 * d + lg) ^ ksw;
        bf16x8 kfr = *reinterpret_cast<const bf16x8*>(&Ks[krow * 192 + kc * 8]);
        sa[jf] = __builtin_amdgcn_mfma_f32_16x16x32_bf16(kfr, qfr[d], sa[jf], 0, 0, 0);
      }
    }
    __builtin_amdgcn_s_setprio(0);

    // lane holds 16 P-values (keys jf*16+lg*4+r) for query qi = q0 + l15
    const bool full = (j0 + 63 <= q0);
    const int qi = q0 + l15;
    float sv[16];
#pragma unroll
    for (int jf = 0; jf < 4; ++jf)
#pragma unroll
      for (int r = 0; r < 4; ++r) {
        float x = sa[jf][r] * scale;
        if (!full) {
          const int j = j0 + jf * 16 + lg * 4 + r;
          if (j > qi) x = -1e30f;
        }
        sv[jf * 4 + r] = x;
      }

    // ---- tile max: in-register tree + 2 cross-lane rounds ----
    float a8[8];
#pragma unroll
    for (int i = 0; i < 8; ++i) a8[i] = fmaxf(sv[i], sv[i + 8]);
#pragma unroll
    for (int i = 0; i < 4; ++i) a8[i] = fmaxf(a8[i], a8[i + 4]);
    float mx = fmaxf(fmaxf(a8[0], a8[1]), fmaxf(a8[2], a8[3]));
    mx = fmaxf(mx, __shfl_xor(mx, 16, 64));
    mx = fmaxf(mx, __shfl_xor(mx, 32, 64));

    // ---- defer-max (T13): rescale only if max grew by > 8 ----
    if (__any(mx > mrun + 8.0f)) {
      const float mn = fmaxf(mrun, mx);
      const float alpha = __expf(mrun - mn);
      mrun = mn;
      lsum *= alpha;
      float af[4];
#pragma unroll
      for (int r = 0; r < 4; ++r) af[r] = __shfl(alpha, lg * 4 + r, 16);
#pragma unroll
      for (int dt = 0; dt < 8; ++dt)
#pragma unroll
        for (int r = 0; r < 4; ++r) o[dt][r] *= af[r];
    }

    // ---- exp + row sum (in-register tree + 2 rounds) ----
#pragma unroll
    for (int i = 0; i < 16; ++i) sv[i] = __expf(sv[i] - mrun);
    float s8[8];
#pragma unroll
    for (int i = 0; i < 8; ++i) s8[i] = sv[i] + sv[i + 8];
#pragma unroll
    for (int i = 0; i < 4; ++i) s8[i] = s8[i] + s8[i + 4];
    float sm = (s8[0] + s8[1]) + (s8[2] + s8[3]);
    sm += __shfl_xor(sm, 16, 64);
    sm += __shfl_xor(sm, 32, 64);
    lsum += sm;

    // ---- P -> per-wave swizzled LDS ([16 q][64 key], chunk ^= q&7) ----
#pragma unroll
    for (int jf = 0; jf < 4; ++jf) {
      bf16x4 pk;
#pragma unroll
      for (int r = 0; r < 4; ++r) pk[r] = (bf16_t)sv[jf * 4 + r];
      const int key = jf * 16 + lg * 4;
      *reinterpret_cast<bf16x4*>(
          &Ps[w * 1024 + l15 * 64 + (key ^ ((l15 & 7) << 3))]) = pk;
    }
    asm volatile("s_waitcnt lgkmcnt(0)" ::: "memory");
    __builtin_amdgcn_sched_barrier(0);
    bf16x8 pfr[2];
#pragma unroll
    for (int jk = 0; jk < 2; ++jk)
      pfr[jk] = *reinterpret_cast<const bf16x8*>(
          &Ps[w * 1024 + l15 * 64 + (((jk * 4 + lg) ^ (l15 & 7)) << 3)]);

    // ---- PV: 8 d-tiles x 2 j-chunks ----
    __builtin_amdgcn_s_setprio(1);
#pragma unroll
    for (int dt = 0; dt < 8; ++dt) {
      const int vrow = dt * 16 + l15;
      const int vsw = vrow & 7;
#pragma unroll
      for (int jk = 0; jk < 2; ++jk) {
        const int vc = (jk * 4 + lg) ^ vsw;
        bf16x8 vfr = *reinterpret_cast<const bf16x8*>(&Vs[vrow * 64 + vc * 8]);
        o[dt] = __builtin_amdgcn_mfma_f32_16x16x32_bf16(pfr[jk], vfr, o[dt], 0, 0, 0);
      }
    }
    __builtin_amdgcn_s_setprio(0);
  }

  // ---- epilogue: normalize (lsum lives at lane of its query) ----
  const float inv = 1.0f / lsum;
  float iv[4];
#pragma unroll
  for (int r = 0; r < 4; ++r) iv[r] = __shfl(inv, lg * 4 + r, 16);
  const int b = bh >> 4, h = bh & 15;
#pragma unroll
  for (int dt = 0; dt < 8; ++dt)
#pragma unroll
    for (int r = 0; r < 4; ++r) {
      const int s = q0 + lg * 4 + r;
      att[((size_t)b * S_LEN + s) * 2048 + h * 128 + dt * 16 + l15] =
          (bf16_t)(o[dt][r] * iv[r]);
    }
}

// ---------------- host launch ----------------
extern "C" void kernel_launch(void* const* d_in, const int* in_sizes, int n_in,
                              void* d_out, int out_size, void* d_ws, size_t ws_size,
                              hipStream_t stream) {
  const float* x    = (const float*)d_in[0];
  const float* fcos = (const float*)d_in[1];
  const float* fsin = (const float*)d_in[2];
  const float* Wkv  = (const float*)d_in[3];
  const float* Wlq  = (const float*)d_in[4];
  const float* Wq   = (const float*)d_in[5];
  const float* Wk   = (const float*)d_in[6];
  const float* Wv   = (const float*)d_in[7];
  const float* Wqr  = (const float*)d_in[8];
  const float* bqr  = (const float*)d_in[9];
  const float* Wkr  = (const float*)d_in[10];
  const float* bkr  = (const float*)d_in[11];
  const float* Wo   = (const float*)d_in[12];
  const float* bo   = (const float*)d_in[13];
  float* out = (float*)d_out;

  char* ws = (char*)d_ws;
  size_t off = 0;
  auto alloc = [&](size_t bytes) {
    void* p = ws + off;
    off += (bytes + 255) & ~(size_t)255;
    return p;
  };
  bf16_t* xb    = (bf16_t*)alloc((size_t)MROWS * 2048 * 2);
  bf16_t* WcatA = (bf16_t*)alloc((size_t)3072 * 2048 * 2);  // [Wlq|Wkv|Wkr]^T, K=2048
  bf16_t* WcatB = (bf16_t*)alloc((size_t)3072 * 1536 * 2);  // [Wq|Wqr]^T,     K=1536
  bf16_t* WcatC = (bf16_t*)alloc((size_t)4096 * 512 * 2);   // [Wk|Wv]^T,      K=512
  bf16_t* WoT   = (bf16_t*)alloc((size_t)2048 * 2048 * 2);
  bf16_t* cq    = (bf16_t*)alloc((size_t)MROWS * 1536 * 2);
  bf16_t* ckv   = (bf16_t*)alloc((size_t)MROWS * 512 * 2);
  bf16_t* qfb   = (bf16_t*)alloc((size_t)NB * NH * S_LEN * DF * 2);
  bf16_t* kfb   = (bf16_t*)alloc((size_t)NB * NH * S_LEN * DF * 2);
  bf16_t* vTb   = (bf16_t*)alloc((size_t)NB * NH * HDIM * S_LEN * 2);
  bf16_t* attb  = (bf16_t*)alloc((size_t)MROWS * 2048 * 2);

  // 1. convert x
  {
    int n4 = (MROWS * 2048) / 4;
    convert_bf16<<<dim3((n4 + 255) / 256), dim3(256), 0, stream>>>(x, xb, n4);
  }
  // 2. transpose weights into concatenated (N,K) bf16 buffers
  auto tr = [&](const float* in, bf16_t* o_, int K, int N) {
    transpose_bf16<<<dim3(N / 64, K / 64), dim3(256), 0, stream>>>(in, o_, K, N);
  };
  tr(Wlq, WcatA, 2048, 1536);
  tr(Wkv, WcatA + (size_t)1536 * 2048, 2048, 512);
  tr(Wkr, WcatA + (size_t)2048 * 2048, 2048, 1024);
  tr(Wq,  WcatB, 1536, 2048);
  tr(Wqr, WcatB + (size_t)2048 * 1536, 1536, 1024);
  tr(Wk,  WcatC, 512, 2048);
  tr(Wv,  WcatC + (size_t)2048 * 512, 512, 2048);
  tr(Wo,  WoT, 2048, 2048);

  EpiParams ep{};

  // 3. fused: [cq | ckv | kr-rope->kf] = xb @ WcatA^T   (N=3072, K=2048)
  ep = {cq, ckv, kfb, nullptr, bkr, fcos, fsin};
  gemm_bt<5><<<dim3(3072 / 128, MROWS / 128), dim3(256), 0, stream>>>(
      xb, WcatA, MROWS, 3072, 2048, ep);
  // 4. fused: [q->qf | qr-rope->qf] = cq @ WcatB^T      (N=3072, K=1536)
  ep = {qfb, nullptr, nullptr, nullptr, bqr, fcos, fsin};
  gemm_bt<6><<<dim3(3072 / 128, MROWS / 128), dim3(256), 0, stream>>>(
      cq, WcatB, MROWS, 3072, 1536, ep);
  // 5. fused: [k->kf | v->vT] = ckv @ WcatC^T           (N=4096, K=512)
  ep = {kfb, vTb, nullptr, nullptr, nullptr, nullptr, nullptr};
  gemm_bt<7><<<dim3(4096 / 128, MROWS / 128), dim3(256), 0, stream>>>(
      ckv, WcatC, MROWS, 4096, 512, ep);
  // 6. attention: 1D grid, XCD-grouped swizzle inside the kernel
  attn_fwd<<<dim3(512), dim3(512), 0, stream>>>(qfb, kfb, vTb, attb);
  // 7. out = att @ Wo + bo  (f32)
  ep = {nullptr, nullptr, nullptr, out, bo, nullptr, nullptr};
  gemm_bt<1><<<dim3(2048 / 128, MROWS / 128), dim3(256), 0, stream>>>(
      attb, WoT, MROWS, 2048, 2048, ep);
}

// Round 8
// 364.856 us; speedup vs baseline: 1.5105x; 1.0667x over previous
//
#include <hip/hip_runtime.h>
#include <hip/hip_bf16.h>
#include <stdint.h>

#define S_LEN 2048
#define NB 2
#define NH 16
#define HDIM 128
#define RDIM 64
#define DF 192          // HDIM + RDIM
#define MROWS 4096      // NB * S_LEN

typedef __bf16 bf16_t;
typedef __attribute__((ext_vector_type(8))) __bf16 bf16x8;
typedef __attribute__((ext_vector_type(4))) __bf16 bf16x4;
typedef __attribute__((ext_vector_type(4))) float f32x4;
typedef __attribute__((ext_vector_type(4))) float float4v;

__device__ __forceinline__ void gload_lds16(const bf16_t* g, bf16_t* l) {
  __builtin_amdgcn_global_load_lds(
      (const __attribute__((address_space(1))) void*)g,
      (__attribute__((address_space(3))) void*)l, 16, 0, 0);
}

// ---------------- convert f32 -> bf16 (contiguous) ----------------
__global__ __launch_bounds__(256) void convert_bf16(const float* __restrict__ in,
                                                    bf16_t* __restrict__ out, int n4) {
  int i = blockIdx.x * 256 + threadIdx.x;
  if (i >= n4) return;
  float4v v = *reinterpret_cast<const float4v*>(&in[(size_t)i * 4]);
  bf16x4 o;
  o[0] = (bf16_t)v[0]; o[1] = (bf16_t)v[1]; o[2] = (bf16_t)v[2]; o[3] = (bf16_t)v[3];
  *reinterpret_cast<bf16x4*>(&out[(size_t)i * 4]) = o;
}

// ---------------- fused transpose: all 8 weights in one launch ----------------
struct TrDesc { const float* src; bf16_t* dst; int K; int N; int nbx; int base; };
struct TrPack { TrDesc d[8]; };

__global__ __launch_bounds__(256) void transpose_all(TrPack p) {
  __shared__ float t[64][65];
  const int bid = blockIdx.x;
  int m = 0;
#pragma unroll
  for (int i = 1; i < 8; ++i) m += (bid >= p.d[i].base);
  const TrDesc td = p.d[m];
  const int local = bid - td.base;
  const int n0 = (local % td.nbx) * 64, k0 = (local / td.nbx) * 64;
  const int tx = threadIdx.x & 63, ty = threadIdx.x >> 6;
#pragma unroll
  for (int i = ty; i < 64; i += 4)
    t[i][tx] = td.src[(size_t)(k0 + i) * td.N + n0 + tx];
  __syncthreads();
#pragma unroll
  for (int i = ty; i < 64; i += 4)
    td.dst[(size_t)(n0 + i) * td.K + k0 + tx] = (bf16_t)t[tx][i];
}

// ---------------- GEMM body: C(M,N) = A(M,K) * Bt(N,K)^T ----------------
// MODE 1: f32 out + bias (final projection)
// MODE 5: fused xb@[Wlq|Wkv|Wkr]: col<1536 -> cq ; col<2048 -> ckv ; else kr rope->kf
// MODE 6: fused cq@[Wq|Wqr]:      col<2048 -> qf d<128 ; else qr rope->qf
// MODE 7: fused ckv@[Wk|Wv]:      col<2048 -> kf d<128 ; else v -> vT
struct EpiParams {
  bf16_t* o0;
  bf16_t* o1;
  bf16_t* o2;
  float* outf;
  const float* bias;
  const float* cosb;
  const float* sinb;
};

template <int MODE>
__device__ __forceinline__ void gemm_body(const bf16_t* __restrict__ A,
                                          const bf16_t* __restrict__ Bt,
                                          int N, int K, int m0, int n0,
                                          bf16_t* As, bf16_t* Bs, EpiParams ep) {
  const int tid = threadIdx.x;
  const int lane = tid & 63, w = tid >> 6;
  const int l15 = lane & 15, lg = lane >> 4;
  const int mw = (w >> 1) * 64, nw = (w & 1) * 64;

  f32x4 acc[4][4] = {};
  const int row_ld = tid >> 2;            // 0..63
  const int col8 = (tid & 3) * 8;
  const bf16_t* ag = A + (size_t)(m0 + row_ld) * K + col8;
  const bf16_t* bg = Bt + (size_t)(n0 + row_ld) * K + col8;
  const unsigned wbase = (unsigned)(tid & ~63u) * 8;  // elems

  for (int k0 = 0; k0 < K; k0 += 32) {
    __syncthreads();
    gload_lds16(ag + k0, As + wbase);
    gload_lds16(ag + (size_t)64 * K + k0, As + 2048 + wbase);
    gload_lds16(bg + k0, Bs + wbase);
    gload_lds16(bg + (size_t)64 * K + k0, Bs + 2048 + wbase);
    __syncthreads();
    bf16x8 a[4], b[4];
#pragma unroll
    for (int i = 0; i < 4; ++i)
      a[i] = *reinterpret_cast<const bf16x8*>(&As[(mw + i * 16 + l15) * 32 + lg * 8]);
#pragma unroll
    for (int i = 0; i < 4; ++i)
      b[i] = *reinterpret_cast<const bf16x8*>(&Bs[(nw + i * 16 + l15) * 32 + lg * 8]);
#pragma unroll
    for (int i = 0; i < 4; ++i)
#pragma unroll
      for (int j = 0; j < 4; ++j)
        acc[i][j] = __builtin_amdgcn_mfma_f32_16x16x32_bf16(a[i], b[j], acc[i][j], 0, 0, 0);
  }

#pragma unroll
  for (int i = 0; i < 4; ++i)
#pragma unroll
    for (int j = 0; j < 4; ++j) {
      const int col = n0 + nw + j * 16 + l15;
#pragma unroll
      for (int r = 0; r < 4; ++r) {
        const int row = m0 + mw + i * 16 + lg * 4 + r;
        float v = acc[i][j][r];
        const int b = row >> 11, s = row & 2047;
        if constexpr (MODE == 1) {
          ep.outf[(size_t)row * N + col] = v + ep.bias[col];
        } else if constexpr (MODE == 5) {
          if (col < 1536) {
            ep.o0[(size_t)row * 1536 + col] = (bf16_t)v;
          } else if (col < 2048) {
            ep.o1[(size_t)row * 512 + (col - 1536)] = (bf16_t)v;
          } else {
            const int c2 = col - 2048;
            float vb = v + ep.bias[c2];
            float other = __shfl_xor(vb, 1, 64);
            const int h = c2 >> 6, dr = c2 & 63;
            const int fi = dr >> 1;
            const float c = ep.cosb[s * 32 + fi];
            const float sn = ep.sinb[s * 32 + fi];
            const float o = (c2 & 1) ? (other * sn + vb * c) : (vb * c - other * sn);
            ep.o2[(((size_t)(b * NH + h)) * S_LEN + s) * DF + 128 + dr] = (bf16_t)o;
          }
        } else if constexpr (MODE == 6) {
          if (col < 2048) {
            const int h = col >> 7, d = col & 127;
            ep.o0[(((size_t)(b * NH + h)) * S_LEN + s) * DF + d] = (bf16_t)v;
          } else {
            const int c2 = col - 2048;
            float vb = v + ep.bias[c2];
            float other = __shfl_xor(vb, 1, 64);
            const int h = c2 >> 6, dr = c2 & 63;
            const int fi = dr >> 1;
            const float c = ep.cosb[s * 32 + fi];
            const float sn = ep.sinb[s * 32 + fi];
            const float o = (c2 & 1) ? (other * sn + vb * c) : (vb * c - other * sn);
            ep.o0[(((size_t)(b * NH + h)) * S_LEN + s) * DF + 128 + dr] = (bf16_t)o;
          }
        } else {  // MODE 7
          if (col < 2048) {
            const int h = col >> 7, d = col & 127;
            ep.o0[(((size_t)(b * NH + h)) * S_LEN + s) * DF + d] = (bf16_t)v;
          } else {
            const int c2 = col - 2048;
            const int h = c2 >> 7, d = c2 & 127;
            ep.o1[(((size_t)(b * NH + h)) * HDIM + d) * S_LEN + s] = (bf16_t)v;
          }
        }
      }
    }
}

template <int MODE>
__global__ __launch_bounds__(256) void gemm_bt(const bf16_t* __restrict__ A,
                                               const bf16_t* __restrict__ Bt,
                                               int N, int K, EpiParams ep) {
  __shared__ alignas(16) bf16_t As[128 * 32];
  __shared__ alignas(16) bf16_t Bs[128 * 32];
  // T1: XCD-aware block swizzle (nwg % 8 == 0).
  const int gx = gridDim.x;
  const int nwg = gx * gridDim.y;
  int flat = blockIdx.y * gx + blockIdx.x;
  flat = (flat & 7) * (nwg >> 3) + (flat >> 3);
  const int m0 = (flat / gx) * 128, n0 = (flat % gx) * 128;
  gemm_body<MODE>(A, Bt, N, K, m0, n0, As, Bs, ep);
}

// Fused launch: blocks [0,768) run MODE 6 (N=3072,K=1536); [768,1792) MODE 7
// (N=4096,K=512). Both consume gemm5 outputs and are independent.
__global__ __launch_bounds__(256) void gemm_bt67(const bf16_t* __restrict__ A6,
                                                 const bf16_t* __restrict__ Bt6,
                                                 const bf16_t* __restrict__ A7,
                                                 const bf16_t* __restrict__ Bt7,
                                                 EpiParams ep6, EpiParams ep7) {
  __shared__ alignas(16) bf16_t As[128 * 32];
  __shared__ alignas(16) bf16_t Bs[128 * 32];
  const int bid = blockIdx.x;
  if (bid < 768) {
    int flat = (bid & 7) * 96 + (bid >> 3);     // T1 within 768
    const int m0 = (flat / 24) * 128, n0 = (flat % 24) * 128;
    gemm_body<6>(A6, Bt6, 3072, 1536, m0, n0, As, Bs, ep6);
  } else {
    int b2 = bid - 768;
    int flat = (b2 & 7) * 128 + (b2 >> 3);      // T1 within 1024
    const int m0 = (flat / 32) * 128, n0 = (flat % 32) * 128;
    gemm_body<7>(A7, Bt7, 4096, 512, m0, n0, As, Bs, ep7);
  }
}

// ---------------- flash attention (causal), swapped softmax, 32q/wave ----------------
// qf,kf: (B,H,S,192) bf16 ; vT: (B,H,128,S) bf16 ; att: (B,S,H*128) bf16
// Block: 4 waves x 32 q-rows = 128 q rows. KV tile = 64 keys staged to LDS
// (2-barrier gload_lds). Each wave holds TWO 16-row m-frags sharing every K/V
// fragment -> LDS reads per MFMA 1.0 -> 0.5 (the r7 bottleneck). Swapped QK^T
// (mfma(K,Q)): lane owns one query's P-row per m-frag -> in-register softmax
// tree + 2 shfl_xor + defer-max (T13). LDS 56 KB -> 2 blocks/CU.
__global__ __launch_bounds__(256, 2) void attn_fwd(const bf16_t* __restrict__ qf,
                                                   const bf16_t* __restrict__ kf,
                                                   const bf16_t* __restrict__ vT,
                                                   bf16_t* __restrict__ att) {
  const int tid = threadIdx.x;
  const int lane = tid & 63, w = tid >> 6;   // w: 0..3
  const int l15 = lane & 15, lg = lane >> 4;
  // XCD-grouped swizzle: block l -> XCD l%8; 4 bh per XCD, heavy q first.
  const int l = blockIdx.x;                  // 0..511
  const int bh = (l & 7) * 4 + ((l >> 3) & 3);
  const int qchunk = l >> 5;                 // 0..15
  const int qb0 = (15 - qchunk) * 128;
  const int q0 = qb0 + w * 32;
  const float scale = 0.07216878364870322f;  // 1/sqrt(192)

  __shared__ alignas(16) bf16_t Ks[64 * 192];     // 24 KB (swizzled)
  __shared__ alignas(16) bf16_t Vs[128 * 64];     // 16 KB (swizzled)
  __shared__ alignas(16) bf16_t Ps[4 * 2048];     // 16 KB per-wave P (2 m-frags)

  // Q fragments (B-operand), two m-frags, held for the whole loop
  bf16x8 qfr[2][6];
#pragma unroll
  for (int mf = 0; mf < 2; ++mf) {
    const bf16_t* qptr = qf + ((size_t)bh * S_LEN + q0 + mf * 16 + l15) * DF + lg * 8;
#pragma unroll
    for (int d = 0; d < 6; ++d)
      qfr[mf][d] = *reinterpret_cast<const bf16x8*>(qptr + d * 32);
  }

  f32x4 o[2][8] = {};
  float mrun[2] = {-1e30f, -1e30f}, lsum[2] = {0.0f, 0.0f};

  const bf16_t* kb0 = kf + (size_t)bh * S_LEN * DF;
  const bf16_t* vb0 = vT + (size_t)bh * HDIM * S_LEN;
  const int njt = qb0 / 64 + 2;
  const int wslot = tid & ~63;

  for (int jt = 0; jt < njt; ++jt) {
    const int j0 = jt * 64;
    __syncthreads();  // previous tile's reads complete before overwrite
    // ---- stage K tile: 1536 16B-slots, 6 issues x 256 ----
    const bf16_t* kTile = kb0 + (size_t)j0 * DF;
#pragma unroll
    for (int i = 0; i < 6; ++i) {
      const int s = i * 256 + tid;
      const int row = s / 24;
      const int c = s - row * 24;
      const int cs = c ^ (row & 7);
      gload_lds16(kTile + (size_t)row * DF + cs * 8,
                  Ks + (size_t)(i * 256 + wslot) * 8);
    }
    // ---- stage V tile: 1024 16B-slots, 4 issues x 256 ----
    const bf16_t* vTile = vb0 + j0;
#pragma unroll
    for (int i = 0; i < 4; ++i) {
      const int s = i * 256 + tid;
      const int row = s >> 3;
      const int c = s & 7;
      const int cs = c ^ (row & 7);
      gload_lds16(vTile + (size_t)row * S_LEN + cs * 8,
                  Vs + (size_t)(i * 256 + wslot) * 8);
    }
    __syncthreads();  // staged data visible

    if (j0 > q0 + 31) continue;  // fully masked for this wave

    // ---- QK^T swapped, kfr shared across m-frags: 24 reads -> 48 MFMA ----
    f32x4 sa[2][4] = {};
    __builtin_amdgcn_s_setprio(1);
#pragma unroll
    for (int jf = 0; jf < 4; ++jf) {
      const int krow = jf * 16 + l15;
      const int ksw = krow & 7;
#pragma unroll
      for (int d = 0; d < 6; ++d) {
        const int kc = (4 * d + lg) ^ ksw;
        bf16x8 kfr = *reinterpret_cast<const bf16x8*>(&Ks[krow * 192 + kc * 8]);
#pragma unroll
        for (int mf = 0; mf < 2; ++mf)
          sa[mf][jf] =
              __builtin_amdgcn_mfma_f32_16x16x32_bf16(kfr, qfr[mf][d], sa[mf][jf], 0, 0, 0);
      }
    }
    __builtin_amdgcn_s_setprio(0);

    // ---- per-m-frag softmax (lane owns query qi = q0+mf*16+l15) ----
#pragma unroll
    for (int mf = 0; mf < 2; ++mf) {
      const int qi = q0 + mf * 16 + l15;
      const bool full = (j0 + 63 <= q0 + mf * 16);
      float sv[16];
#pragma unroll
      for (int jf = 0; jf < 4; ++jf)
#pragma unroll
        for (int r = 0; r < 4; ++r) {
          float x = sa[mf][jf][r] * scale;
          if (!full) {
            const int j = j0 + jf * 16 + lg * 4 + r;
            if (j > qi) x = -1e30f;
          }
          sv[jf * 4 + r] = x;
        }

      float a8[8];
#pragma unroll
      for (int i = 0; i < 8; ++i) a8[i] = fmaxf(sv[i], sv[i + 8]);
#pragma unroll
      for (int i = 0; i < 4; ++i) a8[i] = fmaxf(a8[i], a8[i + 4]);
      float mx = fmaxf(fmaxf(a8[0], a8[1]), fmaxf(a8[2], a8[3]));
      mx = fmaxf(mx, __shfl_xor(mx, 16, 64));
      mx = fmaxf(mx, __shfl_xor(mx, 32, 64));

      if (__any(mx > mrun[mf] + 8.0f)) {   // defer-max (T13)
        const float mn = fmaxf(mrun[mf], mx);
        const float alpha = __expf(mrun[mf] - mn);
        mrun[mf] = mn;
        lsum[mf] *= alpha;
        float af[4];
#pragma unroll
        for (int r = 0; r < 4; ++r) af[r] = __shfl(alpha, lg * 4 + r, 16);
#pragma unroll
        for (int dt = 0; dt < 8; ++dt)
#pragma unroll
          for (int r = 0; r < 4; ++r) o[mf][dt][r] *= af[r];
      }

#pragma unroll
      for (int i = 0; i < 16; ++i) sv[i] = __expf(sv[i] - mrun[mf]);
      float s8[8];
#pragma unroll
      for (int i = 0; i < 8; ++i) s8[i] = sv[i] + sv[i + 8];
#pragma unroll
      for (int i = 0; i < 4; ++i) s8[i] = s8[i] + s8[i + 4];
      float sm = (s8[0] + s8[1]) + (s8[2] + s8[3]);
      sm += __shfl_xor(sm, 16, 64);
      sm += __shfl_xor(sm, 32, 64);
      lsum[mf] += sm;

      // P -> per-wave swizzled LDS ([16 q][64 key], key-chunk ^= q&7)
#pragma unroll
      for (int jf = 0; jf < 4; ++jf) {
        bf16x4 pk;
#pragma unroll
        for (int r = 0; r < 4; ++r) pk[r] = (bf16_t)sv[jf * 4 + r];
        const int key = jf * 16 + lg * 4;
        *reinterpret_cast<bf16x4*>(
            &Ps[w * 2048 + mf * 1024 + l15 * 64 + (key ^ ((l15 & 7) << 3))]) = pk;
      }
    }
    asm volatile("s_waitcnt lgkmcnt(0)" ::: "memory");
    __builtin_amdgcn_sched_barrier(0);
    bf16x8 pfr[2][2];
#pragma unroll
    for (int mf = 0; mf < 2; ++mf)
#pragma unroll
      for (int jk = 0; jk < 2; ++jk)
        pfr[mf][jk] = *reinterpret_cast<const bf16x8*>(
            &Ps[w * 2048 + mf * 1024 + l15 * 64 + (((jk * 4 + lg) ^ (l15 & 7)) << 3)]);

    // ---- PV: vfr shared across m-frags: 16 reads -> 32 MFMA ----
    __builtin_amdgcn_s_setprio(1);
#pragma unroll
    for (int dt = 0; dt < 8; ++dt) {
      const int vrow = dt * 16 + l15;
      const int vsw = vrow & 7;
#pragma unroll
      for (int jk = 0; jk < 2; ++jk) {
        const int vc = (jk * 4 + lg) ^ vsw;
        bf16x8 vfr = *reinterpret_cast<const bf16x8*>(&Vs[vrow * 64 + vc * 8]);
#pragma unroll
        for (int mf = 0; mf < 2; ++mf)
          o[mf][dt] =
              __builtin_amdgcn_mfma_f32_16x16x32_bf16(pfr[mf][jk], vfr, o[mf][dt], 0, 0, 0);
      }
    }
    __builtin_amdgcn_s_setprio(0);
  }

  // ---- epilogue ----
  const int b = bh >> 4, h = bh & 15;
#pragma unroll
  for (int mf = 0; mf < 2; ++mf) {
    const float inv = 1.0f / lsum[mf];
    float iv[4];
#pragma unroll
    for (int r = 0; r < 4; ++r) iv[r] = __shfl(inv, lg * 4 + r, 16);
#pragma unroll
    for (int dt = 0; dt < 8; ++dt)
#pragma unroll
      for (int r = 0; r < 4; ++r) {
        const int s = q0 + mf * 16 + lg * 4 + r;
        att[((size_t)b * S_LEN + s) * 2048 + h * 128 + dt * 16 + l15] =
            (bf16_t)(o[mf][dt][r] * iv[r]);
      }
  }
}

// ---------------- host launch ----------------
extern "C" void kernel_launch(void* const* d_in, const int* in_sizes, int n_in,
                              void* d_out, int out_size, void* d_ws, size_t ws_size,
                              hipStream_t stream) {
  const float* x    = (const float*)d_in[0];
  const float* fcos = (const float*)d_in[1];
  const float* fsin = (const float*)d_in[2];
  const float* Wkv  = (const float*)d_in[3];
  const float* Wlq  = (const float*)d_in[4];
  const float* Wq   = (const float*)d_in[5];
  const float* Wk   = (const float*)d_in[6];
  const float* Wv   = (const float*)d_in[7];
  const float* Wqr  = (const float*)d_in[8];
  const float* bqr  = (const float*)d_in[9];
  const float* Wkr  = (const float*)d_in[10];
  const float* bkr  = (const float*)d_in[11];
  const float* Wo   = (const float*)d_in[12];
  const float* bo   = (const float*)d_in[13];
  float* out = (float*)d_out;

  char* ws = (char*)d_ws;
  size_t off = 0;
  auto alloc = [&](size_t bytes) {
    void* p = ws + off;
    off += (bytes + 255) & ~(size_t)255;
    return p;
  };
  bf16_t* xb    = (bf16_t*)alloc((size_t)MROWS * 2048 * 2);
  bf16_t* WcatA = (bf16_t*)alloc((size_t)3072 * 2048 * 2);  // [Wlq|Wkv|Wkr]^T, K=2048
  bf16_t* WcatB = (bf16_t*)alloc((size_t)3072 * 1536 * 2);  // [Wq|Wqr]^T,     K=1536
  bf16_t* WcatC = (bf16_t*)alloc((size_t)4096 * 512 * 2);   // [Wk|Wv]^T,      K=512
  bf16_t* WoT   = (bf16_t*)alloc((size_t)2048 * 2048 * 2);
  bf16_t* cq    = (bf16_t*)alloc((size_t)MROWS * 1536 * 2);
  bf16_t* ckv   = (bf16_t*)alloc((size_t)MROWS * 512 * 2);
  bf16_t* qfb   = (bf16_t*)alloc((size_t)NB * NH * S_LEN * DF * 2);
  bf16_t* kfb   = (bf16_t*)alloc((size_t)NB * NH * S_LEN * DF * 2);
  bf16_t* vTb   = (bf16_t*)alloc((size_t)NB * NH * HDIM * S_LEN * 2);
  bf16_t* attb  = (bf16_t*)alloc((size_t)MROWS * 2048 * 2);

  // 1. convert x
  {
    int n4 = (MROWS * 2048) / 4;
    convert_bf16<<<dim3((n4 + 255) / 256), dim3(256), 0, stream>>>(x, xb, n4);
  }
  // 2. all 8 transposes in one launch
  {
    TrPack p;
    int base = 0;
    auto set = [&](int i, const float* s, bf16_t* d, int K, int N) {
      p.d[i] = {s, d, K, N, N / 64, base};
      base += (N / 64) * (K / 64);
    };
    set(0, Wlq, WcatA, 2048, 1536);
    set(1, Wkv, WcatA + (size_t)1536 * 2048, 2048, 512);
    set(2, Wkr, WcatA + (size_t)2048 * 2048, 2048, 1024);
    set(3, Wq,  WcatB, 1536, 2048);
    set(4, Wqr, WcatB + (size_t)2048 * 1536, 1536, 1024);
    set(5, Wk,  WcatC, 512, 2048);
    set(6, Wv,  WcatC + (size_t)2048 * 512, 512, 2048);
    set(7, Wo,  WoT, 2048, 2048);
    transpose_all<<<dim3(base), dim3(256), 0, stream>>>(p);
  }

  EpiParams ep{}, ep2{};

  // 3. fused: [cq | ckv | kr-rope->kf] = xb @ WcatA^T   (N=3072, K=2048)
  ep = {cq, ckv, kfb, nullptr, bkr, fcos, fsin};
  gemm_bt<5><<<dim3(3072 / 128, MROWS / 128), dim3(256), 0, stream>>>(
      xb, WcatA, 3072, 2048, ep);
  // 4+5. fused single launch: {q,qr->qf} and {k->kf, v->vT}
  ep  = {qfb, nullptr, nullptr, nullptr, bqr, fcos, fsin};
  ep2 = {kfb, vTb, nullptr, nullptr, nullptr, nullptr, nullptr};
  gemm_bt67<<<dim3(1792), dim3(256), 0, stream>>>(cq, WcatB, ckv, WcatC, ep, ep2);
  // 6. attention: 1D grid, XCD-grouped swizzle inside the kernel
  attn_fwd<<<dim3(512), dim3(256), 0, stream>>>(qfb, kfb, vTb, attb);
  // 7. out = att @ Wo + bo  (f32)
  ep = {nullptr, nullptr, nullptr, out, bo, nullptr, nullptr};
  gemm_bt<1><<<dim3(2048 / 128, MROWS / 128), dim3(256), 0, stream>>>(
      attb, WoT, 2048, 2048, ep);
}